// Round 2
// baseline (217.812 us; speedup 1.0000x reference)
//
#include <hip/hip_runtime.h>

// Output (float32, flat): mask_a (8,12,512,512) then mask_b (8,12,512,512).
// Channel groups (c/3): 0=ones, 1=checkerboard(i%2==j%2), 2=row parity i%2,
// 3=col parity j%2.  mask_b = 1 - mask_a everywhere.
//
// Pure pattern write: 384 MiB of stores, zero reads. Floor = write BW.

typedef float f4 __attribute__((ext_vector_type(4)));

// Value LUT indexed by (g*2 + row_parity), giving mask_a at even/odd column:
//   idx: g0/ip0 g0/ip1 g1/ip0 g1/ip1 g2/ip0 g2/ip1 g3/ip0 g3/ip1
//   va0:   1      1      1      0      0      1      0      0   -> 0x27
//   va1:   1      1      0      1      0      1      1      1   -> 0xEB
// mask_b value = va ^ 1.

__global__ __launch_bounds__(256) void picmix_kernel(f4* __restrict__ out,
                                                     unsigned int n4) {
    unsigned int base = blockIdx.x * 1024u + threadIdx.x;  // 4 float4 per thread
#pragma unroll
    for (int k = 0; k < 4; ++k) {
        unsigned int idx4 = base + (unsigned)k * 256u;
        if (idx4 >= n4) return;
        unsigned int id = idx4 << 2;                       // flat float index
        unsigned int t  = (id >= 25165824u) ? 1u : 0u;     // mask_a vs mask_b
        unsigned int g  = ((id >> 18) % 12u) / 3u;         // rule group 0..3
        unsigned int ip = (id >> 9) & 1u;                  // row parity (W=512)
        unsigned int lut = g * 2u + ip;
        float v0 = (float)(((0x27u >> lut) & 1u) ^ t);     // even column
        float v1 = (float)(((0xEBu >> lut) & 1u) ^ t);     // odd column
        f4 v = {v0, v1, v0, v1};                           // cols (0,1,0,1) parity
        __builtin_nontemporal_store(v, &out[idx4]);
    }
}

extern "C" void kernel_launch(void* const* d_in, const int* in_sizes, int n_in,
                              void* d_out, int out_size, void* d_ws, size_t ws_size,
                              hipStream_t stream) {
    // Inputs unused: outputs are deterministic parity masks.
    (void)d_in; (void)in_sizes; (void)n_in; (void)d_ws; (void)ws_size;
    unsigned int n4 = (unsigned int)(out_size / 4);        // 12,582,912 float4
    unsigned int blocks = (n4 + 1023u) / 1024u;            // 12,288 blocks
    picmix_kernel<<<blocks, 256, 0, stream>>>((f4*)d_out, n4);
}